// Round 1
// 372.260 us; speedup vs baseline: 2.4425x; 2.4425x over previous
//
#include <hip/hip_runtime.h>
#include <hip/hip_bf16.h>
#include <math.h>

#define BATCH 4
#define SEQ   4096
#define EMB   1024
#define HD    64
#define RPB   8     // rows per block in projection

#define QBLK  32    // query rows per attention block (2 waves x 16)
#define KBLK  64    // key/value tile

typedef _Float16 half8 __attribute__((ext_vector_type(8)));
typedef float    f32x4 __attribute__((ext_vector_type(4)));

// global->LDS direct staging, 16B per lane, linear LDS dest (wave base + lane*16)
#define GLOAD_LDS16(g, l) __builtin_amdgcn_global_load_lds(                 \
    (const __attribute__((address_space(1))) void*)(g),                     \
    (__attribute__((address_space(3))) void*)(l), 16, 0, 0)

static __device__ __forceinline__ float bf2f(unsigned int u16) {
    union { unsigned int i; float f; } v;
    v.i = u16 << 16;
    return v.f;
}

// --------- dtype detector: bf16 N(0,1) never has exponent>146; fp32 read as
// --------- bf16 halfwords does (~42% of low halves). Deterministic per input.
__global__ void detect_dtype(const unsigned short* __restrict__ x,
                             int* __restrict__ flag)
{
    const int tid = threadIdx.x;
    int big = 0;
    for (int i = tid; i < 2048; i += 64) {
        const int e = (x[i] >> 7) & 0xff;
        if (e > 146) big++;                 // |bf16| > ~1e6 (incl inf/nan)
    }
    #pragma unroll
    for (int off = 32; off; off >>= 1) big += __shfl_xor(big, off);
    if (tid == 0) *flag = (big > 200) ? 0 : 1;   // 0 = fp32 inputs, 1 = bf16
}

// ---------------- QKV projection: [B*S,1024] x [1024,64] x3 -> fp16 -------
// Q,K row-major [b*s][64]; V written TRANSPOSED [b][64][s] so the attention
// PV B-fragments are contiguous-in-key loads.
__global__ __launch_bounds__(192) void qkv_proj(
    const void* __restrict__ xp,
    const void* __restrict__ Wqp, const void* __restrict__ Wkp,
    const void* __restrict__ Wvp, const int* __restrict__ flagp,
    _Float16* __restrict__ Qh, _Float16* __restrict__ Kh,
    _Float16* __restrict__ Vth)
{
    __shared__ float xs[RPB * EMB];        // 32 KB
    const int tid = threadIdx.x;
    const size_t row0 = (size_t)blockIdx.x * RPB;
    const int isbf = *flagp;

    if (isbf) {
        const unsigned int* xu =
            (const unsigned int*)((const unsigned short*)xp + row0 * EMB);
        for (int i = tid; i < RPB * EMB / 2; i += 192) {
            const unsigned int u = xu[i];
            xs[2 * i]     = bf2f(u & 0xffffu);
            xs[2 * i + 1] = bf2f(u >> 16);
        }
    } else {
        const float4* xf = (const float4*)((const float*)xp + row0 * EMB);
        for (int i = tid; i < RPB * EMB / 4; i += 192) {
            const float4 v = xf[i];
            xs[4 * i]     = v.x; xs[4 * i + 1] = v.y;
            xs[4 * i + 2] = v.z; xs[4 * i + 3] = v.w;
        }
    }
    __syncthreads();

    const int m = tid / 64, d = tid & 63;  // wave m owns matrix m, lane = out dim
    const void* Wp = (m == 0) ? Wqp : (m == 1 ? Wkp : Wvp);

    float acc[RPB];
    #pragma unroll
    for (int r = 0; r < RPB; ++r) acc[r] = 0.f;

    if (isbf) {
        const unsigned short* W = (const unsigned short*)Wp;
        for (int e = 0; e < EMB; e += 4) {
            const float w0 = bf2f(W[(e + 0) * HD + d]);
            const float w1 = bf2f(W[(e + 1) * HD + d]);
            const float w2 = bf2f(W[(e + 2) * HD + d]);
            const float w3 = bf2f(W[(e + 3) * HD + d]);
            #pragma unroll
            for (int r = 0; r < RPB; ++r) {
                const float4 xv = *(const float4*)&xs[r * EMB + e];
                acc[r] += xv.x * w0 + xv.y * w1 + xv.z * w2 + xv.w * w3;
            }
        }
    } else {
        const float* W = (const float*)Wp;
        for (int e = 0; e < EMB; e += 4) {
            const float w0 = W[(e + 0) * HD + d];
            const float w1 = W[(e + 1) * HD + d];
            const float w2 = W[(e + 2) * HD + d];
            const float w3 = W[(e + 3) * HD + d];
            #pragma unroll
            for (int r = 0; r < RPB; ++r) {
                const float4 xv = *(const float4*)&xs[r * EMB + e];
                acc[r] += xv.x * w0 + xv.y * w1 + xv.z * w2 + xv.w * w3;
            }
        }
    }

    if (m == 2) {
        // V transposed: Vth[b][d][s]; 8 consecutive s per lane -> one 16B store
        const int bb = (int)(row0 >> 12);        // /SEQ
        const int ss = (int)(row0 & (SEQ - 1));
        half8 hv;
        #pragma unroll
        for (int r = 0; r < RPB; ++r) hv[r] = (_Float16)acc[r];
        *(half8*)&Vth[((size_t)bb * HD + d) * SEQ + ss] = hv;
    } else {
        _Float16* Out = m ? Kh : Qh;
        #pragma unroll
        for (int r = 0; r < RPB; ++r)
            Out[(row0 + r) * HD + d] = (_Float16)acc[r];
    }
}

// ---------------- causal flash attention, fp16 MFMA -----------------------
// Block: 32 query rows, 2 waves x 16 rows. KV tile = 64.
// LDS 16B-slot XOR swizzle: slot ^= (row & 7)  (both staged-source and read
// sides -> involution, rule 21). Kills the stride-128B 16-way conflicts.
__global__ __launch_bounds__(128) void attn_fwd(
    const _Float16* __restrict__ Qh, const _Float16* __restrict__ Kh,
    const _Float16* __restrict__ Vth, const int* __restrict__ flagp,
    void* __restrict__ outp)
{
    __shared__ _Float16 Kt[2][KBLK * HD];    // 2 x 8 KB  [key][dim]
    __shared__ _Float16 Vt[2][HD * KBLK];    // 2 x 8 KB  [dim][key]
    __shared__ _Float16 Pl[2][16 * KBLK];    // 2 KB per wave, P re-shape

    // flat grid 512: b = f&3, j = f>>2; complement pairing so blocks f and
    // f+256 (likely co-resident on one CU) sum to constant causal work.
    const int f  = blockIdx.x;
    const int b  = f & 3;
    const int j  = f >> 2;
    const int qb = (j < 64) ? (127 - 2 * j) : (2 * (j - 64));
    const int q0 = qb * QBLK;

    const int tid  = threadIdx.x;
    const int w    = tid >> 6;       // wave: rows q0+16w .. q0+16w+15
    const int lane = tid & 63;
    const int col  = lane & 15;      // MFMA col / A row selector
    const int kg   = lane >> 4;      // k-chunk selector (0..3)
    const int isbf = *flagp;

    const size_t bo = (size_t)b * SEQ;
    const _Float16* Kb = Kh + bo * HD;
    const _Float16* Vb = Vth + (size_t)b * HD * SEQ;

    // Q A-fragments (row = lane&15, k = kg*8 + j), kept in registers
    const _Float16* Qp = Qh + (bo + q0 + w * 16 + col) * HD;
    const half8 aq0 = *(const half8*)(Qp + kg * 8);
    const half8 aq1 = *(const half8*)(Qp + 32 + kg * 8);

    f32x4 O[4];
    float mreg[4], lreg[4];
    #pragma unroll
    for (int c = 0; c < 4; ++c) O[c] = (f32x4){0.f, 0.f, 0.f, 0.f};
    #pragma unroll
    for (int r = 0; r < 4; ++r) { mreg[r] = -INFINITY; lreg[r] = 0.f; }

    const int nt = q0 / KBLK + 1;    // causal: tiles 0 .. q0/64

    // stage one 64x64 fp16 tile of K (wave 0) and V^T (wave 1) into buf.
    // LDS dest linear; global source slot pre-XORed so a read at
    // slot^(row&7) returns the un-permuted data.
    auto stage = [&](int t, int buf) {
        const int k0 = t * KBLK;
        if (w == 0) {
            const _Float16* g = Kb + (size_t)k0 * HD;
            #pragma unroll
            for (int i = 0; i < 8; ++i) {
                const int c2 = i * 64 + lane;      // 16B chunk id
                const int key = c2 >> 3, slot = c2 & 7;
                GLOAD_LDS16(g + key * HD + ((slot ^ (key & 7)) << 3),
                            &Kt[buf][i * 512]);
            }
        } else {
            const _Float16* g = Vb + k0;
            #pragma unroll
            for (int i = 0; i < 8; ++i) {
                const int c2 = i * 64 + lane;
                const int dim = c2 >> 3, slot = c2 & 7;
                GLOAD_LDS16(g + (size_t)dim * SEQ + ((slot ^ (dim & 7)) << 3),
                            &Vt[buf][i * 512]);
            }
        }
    };

    stage(0, 0);
    int cur = 0;

    for (int t = 0; t < nt; ++t) {
        __syncthreads();                       // tile t staged; tile t-1 reads done
        if (t + 1 < nt) stage(t + 1, cur ^ 1); // prefetch overlaps compute

        const int k0 = t * KBLK;

        // ---- S = Q K^T  (4 col-tiles x 2 k-steps)
        f32x4 S[4];
        #pragma unroll
        for (int c = 0; c < 4; ++c) {
            const int key = c * 16 + col;
            const int sw  = key & 7;
            const half8 bk0 = *(const half8*)&Kt[cur][(key * 8 + (kg ^ sw)) * 8];
            const half8 bk1 = *(const half8*)&Kt[cur][(key * 8 + ((4 + kg) ^ sw)) * 8];
            f32x4 acc = (f32x4){0.f, 0.f, 0.f, 0.f};
            acc = __builtin_amdgcn_mfma_f32_16x16x32_f16(aq0, bk0, acc, 0, 0, 0);
            acc = __builtin_amdgcn_mfma_f32_16x16x32_f16(aq1, bk1, acc, 0, 0, 0);
            S[c] = acc;
        }

        // ---- scale + causal mask (C layout: row = kg*4+r, col = c*16+col)
        const int rowb  = q0 + w * 16 + kg * 4;
        const bool full = (k0 + KBLK - 1) <= (q0 + w * 16);
        float p[4][4];
        #pragma unroll
        for (int c = 0; c < 4; ++c) {
            const int key = k0 + c * 16 + col;
            #pragma unroll
            for (int r = 0; r < 4; ++r) {
                float s = S[c][r] * 0.125f;              // 1/sqrt(64)
                if (!full && key > rowb + r) s = -INFINITY;
                p[c][r] = s;
            }
        }

        // ---- online softmax: row reduce across the 16-lane col group
        float alpha[4];
        #pragma unroll
        for (int r = 0; r < 4; ++r) {
            float v = fmaxf(fmaxf(p[0][r], p[1][r]), fmaxf(p[2][r], p[3][r]));
            v = fmaxf(v, __shfl_xor(v, 1));
            v = fmaxf(v, __shfl_xor(v, 2));
            v = fmaxf(v, __shfl_xor(v, 4));
            v = fmaxf(v, __shfl_xor(v, 8));
            const float mn = fmaxf(mreg[r], v);          // finite: key k0<=row
            alpha[r] = __expf(mreg[r] - mn);             // first tile: exp(-inf)=0
            mreg[r]  = mn;
        }

        // ---- P = exp(s-m); write to swizzled LDS for the PV A-fragment
        #pragma unroll
        for (int c = 0; c < 4; ++c) {
            const int colidx = c * 16 + col;
            #pragma unroll
            for (int r = 0; r < 4; ++r) {
                const float pv = __expf(p[c][r] - mreg[r]);  // masked -> 0
                p[c][r] = pv;
                const int row = kg * 4 + r;
                Pl[w][row * 64 + (colidx ^ ((row & 7) << 3))] = (_Float16)pv;
            }
        }
        #pragma unroll
        for (int r = 0; r < 4; ++r) {
            float v = (p[0][r] + p[1][r]) + (p[2][r] + p[3][r]);
            v += __shfl_xor(v, 1);
            v += __shfl_xor(v, 2);
            v += __shfl_xor(v, 4);
            v += __shfl_xor(v, 8);
            lreg[r] = lreg[r] * alpha[r] + v;
        }

        // ---- rescale O, then O += P V   (same-wave LDS RAW: in-order DS pipe)
        #pragma unroll
        for (int c = 0; c < 4; ++c)
            #pragma unroll
            for (int r = 0; r < 4; ++r)
                O[c][r] *= alpha[r];

        #pragma unroll
        for (int s2 = 0; s2 < 2; ++s2) {
            const int prow = col;                         // A row = lane&15
            const half8 pa = *(const half8*)&Pl[w][prow * 64 +
                ((s2 * 32 + kg * 8) ^ ((prow & 7) << 3))];
            #pragma unroll
            for (int c = 0; c < 4; ++c) {
                const int dim = c * 16 + col;
                const half8 bv = *(const half8*)&Vt[cur][(dim * 8 +
                    ((s2 * 4 + kg) ^ (dim & 7))) * 8];
                O[c] = __builtin_amdgcn_mfma_f32_16x16x32_f16(pa, bv, O[c], 0, 0, 0);
            }
        }
        cur ^= 1;
    }

    // ---- epilogue: normalize and store
    #pragma unroll
    for (int r = 0; r < 4; ++r) {
        const int row = q0 + w * 16 + kg * 4 + r;
        const size_t base = (bo + row) * HD;
        const float il = 1.f / lreg[r];
        if (isbf) {
            #pragma unroll
            for (int c = 0; c < 4; ++c)
                ((__hip_bfloat16*)outp)[base + c * 16 + col] =
                    __float2bfloat16(O[c][r] * il);
        } else {
            #pragma unroll
            for (int c = 0; c < 4; ++c)
                ((float*)outp)[base + c * 16 + col] = O[c][r] * il;
        }
    }
}

extern "C" void kernel_launch(void* const* d_in, const int* in_sizes, int n_in,
                              void* d_out, int out_size, void* d_ws, size_t ws_size,
                              hipStream_t stream)
{
    const void* x  = d_in[0];
    const void* Wq = d_in[1];
    const void* Wk = d_in[2];
    const void* Wv = d_in[3];

    int*      flag = (int*)d_ws;
    _Float16* Qh   = (_Float16*)((char*)d_ws + 256);     // 3 x 2 MB fp16 scratch
    _Float16* Kh   = Qh + (size_t)BATCH * SEQ * HD;
    _Float16* Vth  = Kh + (size_t)BATCH * SEQ * HD;

    detect_dtype<<<1, 64, 0, stream>>>((const unsigned short*)x, flag);

    qkv_proj<<<BATCH * SEQ / RPB, 192, 0, stream>>>(x, Wq, Wk, Wv, flag,
                                                    Qh, Kh, Vth);

    attn_fwd<<<BATCH * SEQ / QBLK, 128, 0, stream>>>(Qh, Kh, Vth, flag, d_out);
}

// Round 2
// 227.473 us; speedup vs baseline: 3.9971x; 1.6365x over previous
//
#include <hip/hip_runtime.h>
#include <hip/hip_bf16.h>
#include <math.h>

#define BATCH 4
#define SEQ   4096
#define EMB   1024
#define HD    64

#define QBLK  32    // query rows per attention block (2 waves x 16)
#define KBLK  64    // key/value tile
#define BM    32    // GEMM rows per block

typedef _Float16 half8 __attribute__((ext_vector_type(8)));
typedef _Float16 half4 __attribute__((ext_vector_type(4)));
typedef float    f32x4 __attribute__((ext_vector_type(4)));

// global->LDS direct staging, 16B per lane, linear LDS dest (wave base + lane*16)
#define GLOAD_LDS16(g, l) __builtin_amdgcn_global_load_lds(                 \
    (const __attribute__((address_space(1))) void*)(g),                     \
    (__attribute__((address_space(3))) void*)(l), 16, 0, 0)

static __device__ __forceinline__ float bf2f(unsigned int u16) {
    union { unsigned int i; float f; } v;
    v.i = u16 << 16;
    return v.f;
}

// --------- dtype detector: bf16 N(0,1) never has exponent>146; fp32 read as
// --------- bf16 halfwords does (~42% of low halves). Deterministic per input.
__global__ void detect_dtype(const unsigned short* __restrict__ x,
                             int* __restrict__ flag)
{
    const int tid = threadIdx.x;
    int big = 0;
    for (int i = tid; i < 2048; i += 64) {
        const int e = (x[i] >> 7) & 0xff;
        if (e > 146) big++;                 // |bf16| > ~1e6 (incl inf/nan)
    }
    #pragma unroll
    for (int off = 32; off; off >>= 1) big += __shfl_xor(big, off);
    if (tid == 0) *flag = (big > 200) ? 0 : 1;   // 0 = fp32 inputs, 1 = bf16
}

// ---------------- W -> fp16, transposed to [n=192][k=1024] ----------------
// Row-major-n, contiguous-k == the MFMA B-fragment layout (verified by the
// attention kernel's K usage). One-off 768 KB op; L2-resident afterwards.
__global__ __launch_bounds__(256) void w_to_fp16t(
    const void* __restrict__ Wqp, const void* __restrict__ Wkp,
    const void* __restrict__ Wvp, const int* __restrict__ flagp,
    _Float16* __restrict__ Wt)
{
    const int gid = blockIdx.x * 256 + threadIdx.x;   // 24576 threads
    const int n   = gid >> 7;                         // 0..191
    const int kc  = (gid & 127) << 3;                 // k chunk base
    const int mat = n >> 6, d = n & 63;
    const void* Wp = (mat == 0) ? Wqp : (mat == 1 ? Wkp : Wvp);

    half8 o;
    if (*flagp) {
        const unsigned short* W = (const unsigned short*)Wp;
        #pragma unroll
        for (int j = 0; j < 8; ++j) o[j] = (_Float16)bf2f(W[(kc + j) * HD + d]);
    } else {
        const float* W = (const float*)Wp;
        #pragma unroll
        for (int j = 0; j < 8; ++j) o[j] = (_Float16)W[(kc + j) * HD + d];
    }
    *(half8*)&Wt[n * EMB + kc] = o;
}

// ---------------- QKV projection as fp16 MFMA GEMM ------------------------
// [16384 x 1024] x [1024 x 192] -> fp16 Q,K row-major + V transposed.
// BM=32 rows/block, 512 blocks (2/CU), 4 waves x 48 cols each.
// x reg-staged (issue-early / write-late) into double-buffered swizzled LDS;
// B-frags straight from L2-resident Wt.
__global__ __launch_bounds__(256) void qkv_gemm(
    const void* __restrict__ xp, const _Float16* __restrict__ Wt,
    const int* __restrict__ flagp,
    _Float16* __restrict__ Qh, _Float16* __restrict__ Kh,
    _Float16* __restrict__ Vth)
{
    __shared__ _Float16 Xs[2][BM * 64];   // 2 x 4 KB, 16B-slot swizzle ^= row&7

    const int tid  = threadIdx.x;
    const int w    = tid >> 6;
    const int lane = tid & 63;
    const int c15  = lane & 15;
    const int kg   = lane >> 4;
    const size_t row0 = (size_t)blockIdx.x * BM;
    const int isbf = *flagp;

    // staging: 1 chunk (8 fp16) per thread: r = tid>>3 (row), s = tid&7 (slot)
    const int sr = tid >> 3, ss = tid & 7;
    const size_t gbase = (row0 + sr) * EMB + ss * 8;
    const int lidx = sr * 64 + ((ss ^ (sr & 7)) << 3);

    float4 f0[2], f1[2];     // fp32 staging regs (cur, next)
    uint4  u0,    u1;        // bf16 staging regs

    auto ldc = [&](int t, float4* f, uint4* u) {
        if (isbf) *u = *(const uint4*)((const unsigned short*)xp + gbase + t * 64);
        else {
            f[0] = *(const float4*)((const float*)xp + gbase + t * 64);
            f[1] = *(const float4*)((const float*)xp + gbase + t * 64 + 4);
        }
    };
    auto wrc = [&](int buf, const float4* f, const uint4* u) {
        half8 h;
        if (isbf) {
            const unsigned int uu[4] = {u->x, u->y, u->z, u->w};
            #pragma unroll
            for (int q = 0; q < 4; ++q) {
                h[2 * q]     = (_Float16)bf2f(uu[q] & 0xffffu);
                h[2 * q + 1] = (_Float16)bf2f(uu[q] >> 16);
            }
        } else {
            const float ff[8] = {f[0].x, f[0].y, f[0].z, f[0].w,
                                 f[1].x, f[1].y, f[1].z, f[1].w};
            #pragma unroll
            for (int q = 0; q < 8; ++q) h[q] = (_Float16)ff[q];
        }
        *(half8*)&Xs[buf][lidx] = h;
    };

    f32x4 acc[2][3];
    #pragma unroll
    for (int mf = 0; mf < 2; ++mf)
        #pragma unroll
        for (int nf = 0; nf < 3; ++nf) acc[mf][nf] = (f32x4){0.f, 0.f, 0.f, 0.f};

    ldc(0, f0, &u0);
    wrc(0, f0, &u0);
    int cur = 0;

    for (int t = 0; t < 16; ++t) {
        if (t + 1 < 16) ldc(t + 1, f1, &u1);     // issue early (T14)
        __syncthreads();                          // buf[cur] staged

        #pragma unroll
        for (int kk = 0; kk < 2; ++kk) {
            half8 a[2], b[3];
            #pragma unroll
            for (int mf = 0; mf < 2; ++mf) {
                const int R = mf * 16 + c15;
                a[mf] = *(const half8*)&Xs[cur][R * 64 +
                        (((kk * 4 + kg) ^ (R & 7)) << 3)];
            }
            #pragma unroll
            for (int nf = 0; nf < 3; ++nf) {
                const int n = w * 48 + nf * 16 + c15;
                b[nf] = *(const half8*)&Wt[n * EMB + t * 64 + kk * 32 + kg * 8];
            }
            #pragma unroll
            for (int mf = 0; mf < 2; ++mf)
                #pragma unroll
                for (int nf = 0; nf < 3; ++nf)
                    acc[mf][nf] = __builtin_amdgcn_mfma_f32_16x16x32_f16(
                        a[mf], b[nf], acc[mf][nf], 0, 0, 0);
        }

        if (t + 1 < 16) wrc(cur ^ 1, f1, &u1);   // write late, other buffer
        cur ^= 1;
    }

    // epilogue: C layout row=kg*4+r, col=c15. Each 16-col fragment lies in one
    // matrix (boundaries are multiples of 16).
    #pragma unroll
    for (int nf = 0; nf < 3; ++nf) {
        const int nc  = w * 48 + nf * 16;
        const int mat = nc >> 6;
        const int d   = (nc & 63) + c15;
        if (mat < 2) {
            _Float16* Out = mat ? Kh : Qh;
            #pragma unroll
            for (int mf = 0; mf < 2; ++mf)
                #pragma unroll
                for (int r = 0; r < 4; ++r)
                    Out[(row0 + mf * 16 + kg * 4 + r) * HD + d] =
                        (_Float16)acc[mf][nf][r];
        } else {
            const int bb = (int)(row0 >> 12);
            const int s0 = (int)(row0 & 4095);
            #pragma unroll
            for (int mf = 0; mf < 2; ++mf) {
                half4 hv;
                #pragma unroll
                for (int r = 0; r < 4; ++r) hv[r] = (_Float16)acc[mf][nf][r];
                // 4 C-rows per lane are consecutive s -> one 8B store
                *(half4*)&Vth[((size_t)bb * HD + d) * SEQ + s0 + mf * 16 + kg * 4] = hv;
            }
        }
    }
}

// ---------------- causal flash attention, fp16 MFMA -----------------------
// Block: 32 query rows, 2 waves x 16 rows. KV tile = 64.
// LDS 16B-slot XOR swizzle: slot ^= (row & 7)  (both staged-source and read
// sides -> involution, rule 21). Kills the stride-128B 16-way conflicts.
__global__ __launch_bounds__(128) void attn_fwd(
    const _Float16* __restrict__ Qh, const _Float16* __restrict__ Kh,
    const _Float16* __restrict__ Vth, const int* __restrict__ flagp,
    void* __restrict__ outp)
{
    __shared__ _Float16 Kt[2][KBLK * HD];    // 2 x 8 KB  [key][dim]
    __shared__ _Float16 Vt[2][HD * KBLK];    // 2 x 8 KB  [dim][key]
    __shared__ _Float16 Pl[2][16 * KBLK];    // 2 KB per wave, P re-shape

    // flat grid 512: b = f&3, j = f>>2; complement pairing so blocks f and
    // f+256 (likely co-resident on one CU) sum to constant causal work.
    const int f  = blockIdx.x;
    const int b  = f & 3;
    const int j  = f >> 2;
    const int qb = (j < 64) ? (127 - 2 * j) : (2 * (j - 64));
    const int q0 = qb * QBLK;

    const int tid  = threadIdx.x;
    const int w    = tid >> 6;       // wave: rows q0+16w .. q0+16w+15
    const int lane = tid & 63;
    const int col  = lane & 15;      // MFMA col / A row selector
    const int kg   = lane >> 4;      // k-chunk selector (0..3)
    const int isbf = *flagp;

    const size_t bo = (size_t)b * SEQ;
    const _Float16* Kb = Kh + bo * HD;
    const _Float16* Vb = Vth + (size_t)b * HD * SEQ;

    // Q A-fragments (row = lane&15, k = kg*8 + j), kept in registers
    const _Float16* Qp = Qh + (bo + q0 + w * 16 + col) * HD;
    const half8 aq0 = *(const half8*)(Qp + kg * 8);
    const half8 aq1 = *(const half8*)(Qp + 32 + kg * 8);

    f32x4 O[4];
    float mreg[4], lreg[4];
    #pragma unroll
    for (int c = 0; c < 4; ++c) O[c] = (f32x4){0.f, 0.f, 0.f, 0.f};
    #pragma unroll
    for (int r = 0; r < 4; ++r) { mreg[r] = -INFINITY; lreg[r] = 0.f; }

    const int nt = q0 / KBLK + 1;    // causal: tiles 0 .. q0/64

    // stage one 64x64 fp16 tile of K (wave 0) and V^T (wave 1) into buf.
    // LDS dest linear; global source slot pre-XORed so a read at
    // slot^(row&7) returns the un-permuted data.
    auto stage = [&](int t, int buf) {
        const int k0 = t * KBLK;
        if (w == 0) {
            const _Float16* g = Kb + (size_t)k0 * HD;
            #pragma unroll
            for (int i = 0; i < 8; ++i) {
                const int c2 = i * 64 + lane;      // 16B chunk id
                const int key = c2 >> 3, slot = c2 & 7;
                GLOAD_LDS16(g + key * HD + ((slot ^ (key & 7)) << 3),
                            &Kt[buf][i * 512]);
            }
        } else {
            const _Float16* g = Vb + k0;
            #pragma unroll
            for (int i = 0; i < 8; ++i) {
                const int c2 = i * 64 + lane;
                const int dim = c2 >> 3, slot = c2 & 7;
                GLOAD_LDS16(g + (size_t)dim * SEQ + ((slot ^ (dim & 7)) << 3),
                            &Vt[buf][i * 512]);
            }
        }
    };

    stage(0, 0);
    int cur = 0;

    for (int t = 0; t < nt; ++t) {
        __syncthreads();                       // tile t staged; tile t-1 reads done
        if (t + 1 < nt) stage(t + 1, cur ^ 1); // prefetch overlaps compute

        const int k0 = t * KBLK;

        // ---- S = Q K^T  (4 col-tiles x 2 k-steps)
        f32x4 S[4];
        #pragma unroll
        for (int c = 0; c < 4; ++c) {
            const int key = c * 16 + col;
            const int sw  = key & 7;
            const half8 bk0 = *(const half8*)&Kt[cur][(key * 8 + (kg ^ sw)) * 8];
            const half8 bk1 = *(const half8*)&Kt[cur][(key * 8 + ((4 + kg) ^ sw)) * 8];
            f32x4 acc = (f32x4){0.f, 0.f, 0.f, 0.f};
            acc = __builtin_amdgcn_mfma_f32_16x16x32_f16(aq0, bk0, acc, 0, 0, 0);
            acc = __builtin_amdgcn_mfma_f32_16x16x32_f16(aq1, bk1, acc, 0, 0, 0);
            S[c] = acc;
        }

        // ---- scale + causal mask (C layout: row = kg*4+r, col = c*16+col)
        const int rowb  = q0 + w * 16 + kg * 4;
        const bool full = (k0 + KBLK - 1) <= (q0 + w * 16);
        float p[4][4];
        #pragma unroll
        for (int c = 0; c < 4; ++c) {
            const int key = k0 + c * 16 + col;
            #pragma unroll
            for (int r = 0; r < 4; ++r) {
                float s = S[c][r] * 0.125f;              // 1/sqrt(64)
                if (!full && key > rowb + r) s = -INFINITY;
                p[c][r] = s;
            }
        }

        // ---- online softmax: row reduce across the 16-lane col group
        float alpha[4];
        #pragma unroll
        for (int r = 0; r < 4; ++r) {
            float v = fmaxf(fmaxf(p[0][r], p[1][r]), fmaxf(p[2][r], p[3][r]));
            v = fmaxf(v, __shfl_xor(v, 1));
            v = fmaxf(v, __shfl_xor(v, 2));
            v = fmaxf(v, __shfl_xor(v, 4));
            v = fmaxf(v, __shfl_xor(v, 8));
            const float mn = fmaxf(mreg[r], v);          // finite: key k0<=row
            alpha[r] = __expf(mreg[r] - mn);             // first tile: exp(-inf)=0
            mreg[r]  = mn;
        }

        // ---- P = exp(s-m); write to swizzled LDS for the PV A-fragment
        #pragma unroll
        for (int c = 0; c < 4; ++c) {
            const int colidx = c * 16 + col;
            #pragma unroll
            for (int r = 0; r < 4; ++r) {
                const float pv = __expf(p[c][r] - mreg[r]);  // masked -> 0
                p[c][r] = pv;
                const int row = kg * 4 + r;
                Pl[w][row * 64 + (colidx ^ ((row & 7) << 3))] = (_Float16)pv;
            }
        }
        #pragma unroll
        for (int r = 0; r < 4; ++r) {
            float v = (p[0][r] + p[1][r]) + (p[2][r] + p[3][r]);
            v += __shfl_xor(v, 1);
            v += __shfl_xor(v, 2);
            v += __shfl_xor(v, 4);
            v += __shfl_xor(v, 8);
            lreg[r] = lreg[r] * alpha[r] + v;
        }

        // ---- rescale O, then O += P V   (same-wave LDS RAW: in-order DS pipe)
        #pragma unroll
        for (int c = 0; c < 4; ++c)
            #pragma unroll
            for (int r = 0; r < 4; ++r)
                O[c][r] *= alpha[r];

        #pragma unroll
        for (int s2 = 0; s2 < 2; ++s2) {
            const int prow = col;                         // A row = lane&15
            const half8 pa = *(const half8*)&Pl[w][prow * 64 +
                ((s2 * 32 + kg * 8) ^ ((prow & 7) << 3))];
            #pragma unroll
            for (int c = 0; c < 4; ++c) {
                const int dim = c * 16 + col;
                const half8 bv = *(const half8*)&Vt[cur][(dim * 8 +
                    ((s2 * 4 + kg) ^ (dim & 7))) * 8];
                O[c] = __builtin_amdgcn_mfma_f32_16x16x32_f16(pa, bv, O[c], 0, 0, 0);
            }
        }
        cur ^= 1;
    }

    // ---- epilogue: normalize and store
    #pragma unroll
    for (int r = 0; r < 4; ++r) {
        const int row = q0 + w * 16 + kg * 4 + r;
        const size_t base = (bo + row) * HD;
        const float il = 1.f / lreg[r];
        if (isbf) {
            #pragma unroll
            for (int c = 0; c < 4; ++c)
                ((__hip_bfloat16*)outp)[base + c * 16 + col] =
                    __float2bfloat16(O[c][r] * il);
        } else {
            #pragma unroll
            for (int c = 0; c < 4; ++c)
                ((float*)outp)[base + c * 16 + col] = O[c][r] * il;
        }
    }
}

extern "C" void kernel_launch(void* const* d_in, const int* in_sizes, int n_in,
                              void* d_out, int out_size, void* d_ws, size_t ws_size,
                              hipStream_t stream)
{
    const void* x  = d_in[0];
    const void* Wq = d_in[1];
    const void* Wk = d_in[2];
    const void* Wv = d_in[3];

    int*      flag = (int*)d_ws;
    _Float16* Qh   = (_Float16*)((char*)d_ws + 256);     // 3 x 2 MB fp16 scratch
    _Float16* Kh   = Qh + (size_t)BATCH * SEQ * HD;
    _Float16* Vth  = Kh + (size_t)BATCH * SEQ * HD;
    _Float16* Wt   = Vth + (size_t)BATCH * SEQ * HD;     // 384 KB fp16 [192][1024]

    detect_dtype<<<1, 64, 0, stream>>>((const unsigned short*)x, flag);

    w_to_fp16t<<<96, 256, 0, stream>>>(Wq, Wk, Wv, flag, Wt);

    qkv_gemm<<<BATCH * SEQ / BM, 256, 0, stream>>>(x, Wt, flag, Qh, Kh, Vth);

    attn_fwd<<<BATCH * SEQ / QBLK, 128, 0, stream>>>(Qh, Kh, Vth, flag, d_out);
}